// Round 4
// baseline (244.679 us; speedup 1.0000x reference)
//
#include <hip/hip_runtime.h>

#define BATCH 8
#define DIM 192
#define HH 128
#define WW 128
#define KS 7
#define PAD 3
#define HID 48
#define KK 49            // KS*KS
#define BN_EPS 1e-5f

#define TILE_H 64
#define SROWS (TILE_H + KS - 1)   // 70
#define SW 136                    // 4 left halo + 128 + 4 right halo (float4-aligned)

// ---------------- Kernel A: global average pool over H*W ----------------
__global__ __launch_bounds__(256) void pool_kernel(const float* __restrict__ x,
                                                   float* __restrict__ pooled) {
    const int bc = blockIdx.x;                       // 0..B*DIM-1 (XCD = bc%8)
    const float4* p = (const float4*)(x + (size_t)bc * HH * WW);
    const int t = threadIdx.x;
    float s = 0.f;
#pragma unroll
    for (int i = 0; i < 16; ++i) {                   // 16384 floats = 4096 float4 / 256 thr
        float4 v = p[t + i * 256];
        s += (v.x + v.y) + (v.z + v.w);
    }
#pragma unroll
    for (int off = 32; off > 0; off >>= 1) s += __shfl_down(s, off, 64);
    __shared__ float wsum[4];
    const int wave = t >> 6, lane = t & 63;
    if (lane == 0) wsum[wave] = s;
    __syncthreads();
    if (t == 0) {
        float tot = (wsum[0] + wsum[1]) + (wsum[2] + wsum[3]);
        pooled[bc] = tot * (1.0f / (HH * WW));
    }
}

// ---------------- Kernel B: fused weight generation ----------------
// Every block redundantly computes y = relu(BN(pooled @ w1^T)) for all 8
// batches (74k FMAs, w1 is 36 KB L2-hot), then each thread produces one
// wdyn output. Removes the serial 1-block y-kernel from the chain.
__global__ __launch_bounds__(256) void wgen_kernel(const float* __restrict__ pooled,
                                                   const float* __restrict__ w1,
                                                   const float* __restrict__ gamma,
                                                   const float* __restrict__ beta,
                                                   const float* __restrict__ mean,
                                                   const float* __restrict__ var,
                                                   const float* __restrict__ w2,
                                                   const float* __restrict__ b2,
                                                   float* __restrict__ wdyn) {
    __shared__ float pool_s[BATCH * DIM];            // 1536 floats
    __shared__ float y_s[BATCH * HID];               // 384 floats
    const int t = threadIdx.x;
    for (int i = t; i < BATCH * DIM; i += 256) pool_s[i] = pooled[i];
    __syncthreads();
    for (int i = t; i < BATCH * HID; i += 256) {
        const int b = i / HID, h = i - b * HID;
        const float4* pr = (const float4*)(pool_s + b * DIM);
        const float4* wr = (const float4*)(w1 + (size_t)h * DIM);
        float acc = 0.f;
#pragma unroll
        for (int j = 0; j < DIM / 4; ++j) {
            float4 pv = pr[j], wv = wr[j];
            acc += pv.x * wv.x + pv.y * wv.y + pv.z * wv.z + pv.w * wv.w;
        }
        float yv = (acc - mean[h]) * rsqrtf(var[h] + BN_EPS) * gamma[h] + beta[h];
        y_s[i] = yv > 0.f ? yv : 0.f;
    }
    __syncthreads();
    const int o = blockIdx.x * 256 + t;              // < B*DIM*KK = 75264
    const int b = o / (DIM * KK);
    const int ol = o - b * (DIM * KK);
    const float4* w2r = (const float4*)(w2 + (size_t)ol * HID);
    const float* yb = y_s + b * HID;
    float acc = b2[ol];
#pragma unroll
    for (int j = 0; j < HID / 4; ++j) {
        float4 wv = w2r[j];
        acc += yb[4 * j] * wv.x + yb[4 * j + 1] * wv.y +
               yb[4 * j + 2] * wv.z + yb[4 * j + 3] * wv.w;
    }
    wdyn[o] = acc;
}

// ---------------- Kernel C: depthwise 7x7 conv, sliding-window ring ----------
// Thread map: c4 = t&31 (4-col group), strip = t>>5 (8 strips x 8 rows).
// Half-waves are 8 rows apart: 8*136 floats == 0 mod 32 banks -> same bank
// phase (2-way aliasing only, free per m136). Each thread slides over 14 input
// rows, 3 ds_read_b128 per row, feeding a 7-deep ring of 4-wide accumulators.
// Grid layout blockIdx = tile*1536 + bc keeps both tiles of bc on XCD bc%8
// (same XCD the pool block used) for L2 reuse of x[bc].
__global__ __launch_bounds__(256) void dwconv_kernel(const float* __restrict__ x,
                                                     const float* __restrict__ wdyn,
                                                     const float* __restrict__ bias,
                                                     float* __restrict__ out) {
    __shared__ float smem[SROWS][SW];                // 70*136*4 = 38080 B
    __shared__ float wk_s[KK];
    const int tile = blockIdx.x / (BATCH * DIM);     // 0..1
    const int bc = blockIdx.x - tile * (BATCH * DIM);
    const int c = bc % DIM;
    const int t = threadIdx.x;
    const int r0 = tile * TILE_H;

    if (t < KK) wk_s[t] = wdyn[(size_t)bc * KK + t];

    // stage rows r0-3 .. r0+66 (zero outside), cols 0..127 -> smem cols 4..131
    const float* xp = x + (size_t)bc * HH * WW;
    for (int idx = t; idx < SROWS * 32; idx += 256) {
        const int r = idx >> 5;
        const int c4 = idx & 31;
        const int gr = r0 - PAD + r;
        float4 v = make_float4(0.f, 0.f, 0.f, 0.f);
        if (gr >= 0 && gr < HH) v = ((const float4*)(xp + (size_t)gr * WW))[c4];
        *((float4*)&smem[r][4 + c4 * 4]) = v;
    }
    if (t < SROWS * 2) {                             // zero halo cols
        const int r = t >> 1;
        float4* p = (float4*)&smem[r][(t & 1) ? 132 : 0];
        *p = make_float4(0.f, 0.f, 0.f, 0.f);
    }
    __syncthreads();

    float wreg[KK];
#pragma unroll
    for (int i = 0; i < KK; ++i) wreg[i] = wk_s[i];
    const float bv = bias[c];

    const int c4 = t & 31;
    const int strip = t >> 5;                        // 0..7
    const int sbase = strip * 8;                     // first smem row of window
    float* outp = out + (size_t)bc * HH * WW + (size_t)(r0 + sbase) * WW + c4 * 4;

    float acc[7][4];
#pragma unroll
    for (int i = 0; i < 7; ++i)
        acc[i][0] = acc[i][1] = acc[i][2] = acc[i][3] = 0.f;

#pragma unroll
    for (int ir = 0; ir < TILE_H / 8 + KS - 1; ++ir) {   // 14 input rows
        const float* srow = &smem[sbase + ir][0];
        const float4 f0 = ((const float4*)srow)[c4];
        const float4 f1 = ((const float4*)srow)[c4 + 1];
        const float4 f2 = ((const float4*)srow)[c4 + 2];
        const float v[12] = {f0.x, f0.y, f0.z, f0.w,
                             f1.x, f1.y, f1.z, f1.w,
                             f2.x, f2.y, f2.z, f2.w};
#pragma unroll
        for (int ky = 0; ky < KS; ++ky) {
            const int o = ir - ky;                   // pending output row
            if (o >= 0 && o < 8) {
                float* a = acc[o % 7];
#pragma unroll
                for (int kx = 0; kx < KS; ++kx) {
                    const float wv = wreg[ky * KS + kx];
                    a[0] += wv * v[1 + kx];
                    a[1] += wv * v[2 + kx];
                    a[2] += wv * v[3 + kx];
                    a[3] += wv * v[4 + kx];
                }
            }
        }
        if (ir >= 6) {                               // output row ir-6 complete
            float* a = acc[(ir - 6) % 7];
            float4 o4 = make_float4(a[0] + bv, a[1] + bv, a[2] + bv, a[3] + bv);
            *((float4*)(outp + (size_t)(ir - 6) * WW)) = o4;
            a[0] = a[1] = a[2] = a[3] = 0.f;
        }
    }
}

extern "C" void kernel_launch(void* const* d_in, const int* in_sizes, int n_in,
                              void* d_out, int out_size, void* d_ws, size_t ws_size,
                              hipStream_t stream) {
    const float* x     = (const float*)d_in[0];
    const float* w1    = (const float*)d_in[1];
    const float* gamma = (const float*)d_in[2];
    const float* beta  = (const float*)d_in[3];
    const float* mean  = (const float*)d_in[4];
    const float* var   = (const float*)d_in[5];
    const float* w2    = (const float*)d_in[6];
    const float* b2    = (const float*)d_in[7];
    const float* bias  = (const float*)d_in[8];
    float* out = (float*)d_out;

    float* pooled = (float*)d_ws;                    // B*DIM
    float* wdyn   = pooled + BATCH * DIM;            // B*DIM*KK

    pool_kernel<<<BATCH * DIM, 256, 0, stream>>>(x, pooled);
    wgen_kernel<<<(BATCH * DIM * KK) / 256, 256, 0, stream>>>(
        pooled, w1, gamma, beta, mean, var, w2, b2, wdyn);
    dwconv_kernel<<<BATCH * DIM * 2, 256, 0, stream>>>(x, wdyn, bias, out);
}

// Round 7
// 238.957 us; speedup vs baseline: 1.0239x; 1.0239x over previous
//
#include <hip/hip_runtime.h>

#define BATCH 8
#define DIM 192
#define HH 128
#define WW 128
#define KS 7
#define PAD 3
#define HID 48
#define KK 49            // KS*KS
#define BN_EPS 1e-5f

#define TILE_H 64
#define SROWS (TILE_H + KS - 1)   // 70
// No column halo in LDS — W=128 is the full image width, col halo is always
// zero padding, handled in compute. Row-major [70][128] is exactly contiguous
// with global x within a channel -> lane-linear global_load_lds DMA.
#define NSLOT (SROWS * (WW / 4))  // 2240 float4 slots (= 35 * 64: wave-uniform!)

// ---------------- Kernel A: global average pool over H*W ----------------
__global__ __launch_bounds__(256) void pool_kernel(const float* __restrict__ x,
                                                   float* __restrict__ pooled) {
    const int bc = blockIdx.x;                       // 0..B*DIM-1
    const float4* p = (const float4*)(x + (size_t)bc * HH * WW);
    const int t = threadIdx.x;
    float s = 0.f;
#pragma unroll
    for (int i = 0; i < 16; ++i) {                   // 16384 floats = 4096 float4 / 256 thr
        float4 v = p[t + i * 256];
        s += (v.x + v.y) + (v.z + v.w);
    }
#pragma unroll
    for (int off = 32; off > 0; off >>= 1) s += __shfl_down(s, off, 64);
    __shared__ float wsum[4];
    const int wave = t >> 6, lane = t & 63;
    if (lane == 0) wsum[wave] = s;
    __syncthreads();
    if (t == 0) {
        float tot = (wsum[0] + wsum[1]) + (wsum[2] + wsum[3]);
        pooled[bc] = tot * (1.0f / (HH * WW));
    }
}

// ---------------- Kernel B: fused weight generation ----------------
__global__ __launch_bounds__(256) void wgen_kernel(const float* __restrict__ pooled,
                                                   const float* __restrict__ w1,
                                                   const float* __restrict__ gamma,
                                                   const float* __restrict__ beta,
                                                   const float* __restrict__ mean,
                                                   const float* __restrict__ var,
                                                   const float* __restrict__ w2,
                                                   const float* __restrict__ b2,
                                                   float* __restrict__ wdyn) {
    __shared__ float pool_s[BATCH * DIM];            // 1536 floats
    __shared__ float y_s[BATCH * HID];               // 384 floats
    const int t = threadIdx.x;
    for (int i = t; i < BATCH * DIM; i += 256) pool_s[i] = pooled[i];
    __syncthreads();
    for (int i = t; i < BATCH * HID; i += 256) {
        const int b = i / HID, h = i - b * HID;
        const float4* pr = (const float4*)(pool_s + b * DIM);
        const float4* wr = (const float4*)(w1 + (size_t)h * DIM);
        float acc = 0.f;
#pragma unroll
        for (int j = 0; j < DIM / 4; ++j) {
            float4 pv = pr[j], wv = wr[j];
            acc += pv.x * wv.x + pv.y * wv.y + pv.z * wv.z + pv.w * wv.w;
        }
        float yv = (acc - mean[h]) * rsqrtf(var[h] + BN_EPS) * gamma[h] + beta[h];
        y_s[i] = yv > 0.f ? yv : 0.f;
    }
    __syncthreads();
    const int o = blockIdx.x * 256 + t;              // < B*DIM*KK = 75264
    const int b = o / (DIM * KK);
    const int ol = o - b * (DIM * KK);
    const float4* w2r = (const float4*)(w2 + (size_t)ol * HID);
    const float* yb = y_s + b * HID;
    float acc = b2[ol];
#pragma unroll
    for (int j = 0; j < HID / 4; ++j) {
        float4 wv = w2r[j];
        acc += yb[4 * j] * wv.x + yb[4 * j + 1] * wv.y +
               yb[4 * j + 2] * wv.z + yb[4 * j + 3] * wv.w;
    }
    wdyn[o] = acc;
}

// ---------------- Kernel C: depthwise 7x7 conv ----------------
// Staging: async global_load_lds DMA, 16B/lane. m104/m108 rule: LDS dest =
// readfirstlane(active) + lane*16, so waves must be FULLY active or FULLY
// inactive. NSLOT = 2240 = 35*64 and each wave spans a contiguous 64-slot
// range, so `s < NSLOT` is wave-uniform -> safe guard (Round-6 bug: without
// it, slots 2240..2303 DMA'd x data over wk_s). Out-of-image (but in-bounds)
// slots take per-lane-clamped sources and are zero-overwritten post-barrier.
// Compute: sliding-window ring, 8 strips x 8 rows, half-waves 8 rows apart
// (8*128 == 0 mod 32 banks -> free 2-way aliasing). Column padding via
// predicated edge reads.
__global__ __launch_bounds__(256) void dwconv_kernel(const float* __restrict__ x,
                                                     const float* __restrict__ wdyn,
                                                     const float* __restrict__ bias,
                                                     float* __restrict__ out) {
    __shared__ float smem[SROWS][WW];                // 70*128*4 = 35840 B
    __shared__ float wk_s[KK];
    const int tile = blockIdx.x & 1;                 // interleaved: both tiles of a
    const int bc = blockIdx.x >> 1;                  // channel dispatch adjacently
    const int c = bc % DIM;
    const int t = threadIdx.x;
    const int r0 = tile * TILE_H;

    if (t < KK) wk_s[t] = wdyn[(size_t)bc * KK + t];

    // valid slot range: tile0 rows -3..-1 out-of-image -> valid s in [96,2240);
    // tile1 rows 128..130 out-of-image -> valid s in [0,2144)
    const int slo = tile ? 0 : PAD * (WW / 4);                 // 0 or 96
    const int shi = tile ? (SROWS - PAD) * (WW / 4) : NSLOT;   // 2144 or 2240
    const float* xbase = x + (size_t)bc * HH * WW + (ptrdiff_t)(r0 - PAD) * WW;

#pragma unroll
    for (int i = 0; i < (NSLOT + 255) / 256; ++i) {  // 9 iters
        const int s = t + i * 256;
        if (s < NSLOT) {                             // wave-uniform (2240 = 35*64)
            int sc = s;                              // clamp SOURCE only (per-lane ok)
            if (sc < slo) sc = slo;
            if (sc >= shi) sc = shi - 4;
            __builtin_amdgcn_global_load_lds(
                (const __attribute__((address_space(1))) void*)(xbase + (size_t)sc * 4),
                (__attribute__((address_space(3))) void*)((float*)smem + (size_t)s * 4),
                16, 0, 0);
        }
    }
    __syncthreads();                                 // drains vmcnt: DMA done
    // zero-fill the 3 out-of-image rows (96 float4 slots)
    if (t < PAD * (WW / 4)) {
        const int zslot = (tile ? (SROWS - PAD) * (WW / 4) : 0) + t;
        ((float4*)smem)[zslot] = make_float4(0.f, 0.f, 0.f, 0.f);
    }
    __syncthreads();

    float wreg[KK];
#pragma unroll
    for (int i = 0; i < KK; ++i) wreg[i] = wk_s[i];
    const float bv = bias[c];

    const int c4 = t & 31;                           // 4-col group
    const int strip = t >> 5;                        // 0..7
    const int sbase = strip * 8;
    float* outp = out + (size_t)bc * HH * WW + (size_t)(r0 + sbase) * WW + c4 * 4;

    float acc[7][4];
#pragma unroll
    for (int i = 0; i < 7; ++i)
        acc[i][0] = acc[i][1] = acc[i][2] = acc[i][3] = 0.f;

#pragma unroll
    for (int ir = 0; ir < TILE_H / 8 + KS - 1; ++ir) {   // 14 input rows
        const float4* row4 = (const float4*)&smem[sbase + ir][0];
        const float4 f1 = row4[c4];
        float4 f0 = make_float4(0.f, 0.f, 0.f, 0.f);
        float4 f2 = make_float4(0.f, 0.f, 0.f, 0.f);
        if (c4 > 0)  f0 = row4[c4 - 1];              // cols -4..-1 (zero at left edge)
        if (c4 < 31) f2 = row4[c4 + 1];              // cols +4..+7 (zero at right edge)
        const float v[12] = {f0.x, f0.y, f0.z, f0.w,
                             f1.x, f1.y, f1.z, f1.w,
                             f2.x, f2.y, f2.z, f2.w};
#pragma unroll
        for (int ky = 0; ky < KS; ++ky) {
            const int o = ir - ky;                   // pending output row
            if (o >= 0 && o < 8) {
                float* a = acc[o % 7];
#pragma unroll
                for (int kx = 0; kx < KS; ++kx) {
                    const float wv = wreg[ky * KS + kx];
                    a[0] += wv * v[1 + kx];
                    a[1] += wv * v[2 + kx];
                    a[2] += wv * v[3 + kx];
                    a[3] += wv * v[4 + kx];
                }
            }
        }
        if (ir >= 6) {                               // output row ir-6 complete
            float* a = acc[(ir - 6) % 7];
            float4 o4 = make_float4(a[0] + bv, a[1] + bv, a[2] + bv, a[3] + bv);
            *((float4*)(outp + (size_t)(ir - 6) * WW)) = o4;
            a[0] = a[1] = a[2] = a[3] = 0.f;
        }
    }
}

extern "C" void kernel_launch(void* const* d_in, const int* in_sizes, int n_in,
                              void* d_out, int out_size, void* d_ws, size_t ws_size,
                              hipStream_t stream) {
    const float* x     = (const float*)d_in[0];
    const float* w1    = (const float*)d_in[1];
    const float* gamma = (const float*)d_in[2];
    const float* beta  = (const float*)d_in[3];
    const float* mean  = (const float*)d_in[4];
    const float* var   = (const float*)d_in[5];
    const float* w2    = (const float*)d_in[6];
    const float* b2    = (const float*)d_in[7];
    const float* bias  = (const float*)d_in[8];
    float* out = (float*)d_out;

    float* pooled = (float*)d_ws;                    // B*DIM
    float* wdyn   = pooled + BATCH * DIM;            // B*DIM*KK

    pool_kernel<<<BATCH * DIM, 256, 0, stream>>>(x, pooled);
    wgen_kernel<<<(BATCH * DIM * KK) / 256, 256, 0, stream>>>(
        pooled, w1, gamma, beta, mean, var, w2, b2, wdyn);
    dwconv_kernel<<<BATCH * DIM * 2, 256, 0, stream>>>(x, wdyn, bias, out);
}

// Round 8
// 235.254 us; speedup vs baseline: 1.0401x; 1.0157x over previous
//
#include <hip/hip_runtime.h>

#define BATCH 8
#define DIM 192
#define HH 128
#define WW 128
#define KS 7
#define PAD 3
#define HID 48
#define KK 49            // KS*KS
#define BN_EPS 1e-5f

#define TILE_H 64
#define SROWS (TILE_H + KS - 1)   // 70
// No column halo in LDS — W=128 is the full image width, col halo is always
// zero padding, handled in compute. Row-major [70][128] is exactly contiguous
// with global x within a channel -> lane-linear global_load_lds DMA.
#define NSLOT (SROWS * (WW / 4))  // 2240 float4 slots (= 35 * 64: wave-uniform!)

// ---------------- Kernel A: global average pool over H*W ----------------
__global__ __launch_bounds__(256) void pool_kernel(const float* __restrict__ x,
                                                   float* __restrict__ pooled) {
    const int bc = blockIdx.x;                       // 0..B*DIM-1
    const float4* p = (const float4*)(x + (size_t)bc * HH * WW);
    const int t = threadIdx.x;
    float s = 0.f;
#pragma unroll
    for (int i = 0; i < 16; ++i) {                   // 16384 floats = 4096 float4 / 256 thr
        float4 v = p[t + i * 256];
        s += (v.x + v.y) + (v.z + v.w);
    }
#pragma unroll
    for (int off = 32; off > 0; off >>= 1) s += __shfl_down(s, off, 64);
    __shared__ float wsum[4];
    const int wave = t >> 6, lane = t & 63;
    if (lane == 0) wsum[wave] = s;
    __syncthreads();
    if (t == 0) {
        float tot = (wsum[0] + wsum[1]) + (wsum[2] + wsum[3]);
        pooled[bc] = tot * (1.0f / (HH * WW));
    }
}

// ---------------- Kernel B: fused weight-gen + depthwise 7x7 conv ----------
// Weight generation is inlined: each block computes y[b][0..47] (48 threads,
// 192-dot each; pooled/w1 are L2-hot) and then its channel's 49 dynamic
// weights (49 threads, 48-dot each; w2 rows c*49..c*49+48 = 9.4 KB, L2-hot
// across the 16 blocks sharing channel c). This removes the separate wgen
// dispatch + launch gap + wdyn global round-trip; the weight math overlaps
// the in-flight LDS DMA.
// Staging: async global_load_lds DMA, 16B/lane. m104/m108 rule: LDS dest =
// readfirstlane(active) + lane*16, so waves must be FULLY active or FULLY
// inactive. NSLOT = 2240 = 35*64 and each wave spans a contiguous 64-slot
// range, so `s < NSLOT` is wave-uniform -> safe guard. Out-of-image (but
// in-bounds) slots take per-lane-clamped sources and are zero-overwritten
// post-barrier. Compute: sliding-window ring, 8 strips x 8 rows, half-waves
// 8 rows apart (8*128 == 0 mod 32 banks -> free 2-way aliasing). Column
// padding via predicated edge reads.
__global__ __launch_bounds__(256) void dwconv_fused_kernel(
        const float* __restrict__ x,
        const float* __restrict__ pooled,
        const float* __restrict__ w1,
        const float* __restrict__ gamma,
        const float* __restrict__ beta,
        const float* __restrict__ mean,
        const float* __restrict__ var,
        const float* __restrict__ w2,
        const float* __restrict__ b2,
        const float* __restrict__ bias,
        float* __restrict__ out) {
    __shared__ float smem[SROWS][WW];                // 70*128*4 = 35840 B
    __shared__ float y_s[HID];
    __shared__ float wk_s[KK];
    const int tile = blockIdx.x & 1;                 // interleaved: both tiles of a
    const int bc = blockIdx.x >> 1;                  // channel dispatch adjacently
    const int b = bc / DIM;
    const int c = bc % DIM;
    const int t = threadIdx.x;
    const int r0 = tile * TILE_H;

    // ---- issue async staging DMA first ----
    // valid slot range: tile0 rows -3..-1 out-of-image -> valid s in [96,2240);
    // tile1 rows 128..130 out-of-image -> valid s in [0,2144)
    const int slo = tile ? 0 : PAD * (WW / 4);                 // 0 or 96
    const int shi = tile ? (SROWS - PAD) * (WW / 4) : NSLOT;   // 2144 or 2240
    const float* xbase = x + (size_t)bc * HH * WW + (ptrdiff_t)(r0 - PAD) * WW;

#pragma unroll
    for (int i = 0; i < (NSLOT + 255) / 256; ++i) {  // 9 iters
        const int s = t + i * 256;
        if (s < NSLOT) {                             // wave-uniform (2240 = 35*64)
            int sc = s;                              // clamp SOURCE only (per-lane ok)
            if (sc < slo) sc = slo;
            if (sc >= shi) sc = shi - 4;
            __builtin_amdgcn_global_load_lds(
                (const __attribute__((address_space(1))) void*)(xbase + (size_t)sc * 4),
                (__attribute__((address_space(3))) void*)((float*)smem + (size_t)s * 4),
                16, 0, 0);
        }
    }

    // ---- inline weight generation, stage 1: y = relu(BN(pooled[b] @ w1^T)) ----
    if (t < HID) {
        const float4* pr = (const float4*)(pooled + b * DIM);
        const float4* wr = (const float4*)(w1 + (size_t)t * DIM);
        float acc = 0.f;
#pragma unroll
        for (int j = 0; j < DIM / 4; ++j) {
            float4 pv = pr[j], wv = wr[j];
            acc += pv.x * wv.x + pv.y * wv.y + pv.z * wv.z + pv.w * wv.w;
        }
        float yv = (acc - mean[t]) * rsqrtf(var[t] + BN_EPS) * gamma[t] + beta[t];
        y_s[t] = yv > 0.f ? yv : 0.f;
    }
    __syncthreads();                                 // y_s visible; DMA drained

    // ---- stage 2: wk[k] = b2 + y . w2row   |   zero-fill 3 halo rows ----
    if (t < KK) {
        const int o = c * KK + t;
        const float4* w2r = (const float4*)(w2 + (size_t)o * HID);
        float acc = b2[o];
#pragma unroll
        for (int j = 0; j < HID / 4; ++j) {
            float4 wv = w2r[j];
            acc += y_s[4 * j] * wv.x + y_s[4 * j + 1] * wv.y +
                   y_s[4 * j + 2] * wv.z + y_s[4 * j + 3] * wv.w;
        }
        wk_s[t] = acc;
    } else if (t >= 160) {                           // 96 threads, 96 float4 slots
        const int zi = t - 160;
        const int zslot = (tile ? (SROWS - PAD) * (WW / 4) : 0) + zi;
        ((float4*)smem)[zslot] = make_float4(0.f, 0.f, 0.f, 0.f);
    }
    __syncthreads();

    float wreg[KK];
#pragma unroll
    for (int i = 0; i < KK; ++i) wreg[i] = wk_s[i];
    const float bv = bias[c];

    const int c4 = t & 31;                           // 4-col group
    const int strip = t >> 5;                        // 0..7
    const int sbase = strip * 8;
    float* outp = out + (size_t)bc * HH * WW + (size_t)(r0 + sbase) * WW + c4 * 4;

    float acc[7][4];
#pragma unroll
    for (int i = 0; i < 7; ++i)
        acc[i][0] = acc[i][1] = acc[i][2] = acc[i][3] = 0.f;

#pragma unroll
    for (int ir = 0; ir < TILE_H / 8 + KS - 1; ++ir) {   // 14 input rows
        const float4* row4 = (const float4*)&smem[sbase + ir][0];
        const float4 f1 = row4[c4];
        float4 f0 = make_float4(0.f, 0.f, 0.f, 0.f);
        float4 f2 = make_float4(0.f, 0.f, 0.f, 0.f);
        if (c4 > 0)  f0 = row4[c4 - 1];              // cols -4..-1 (zero at left edge)
        if (c4 < 31) f2 = row4[c4 + 1];              // cols +4..+7 (zero at right edge)
        const float v[12] = {f0.x, f0.y, f0.z, f0.w,
                             f1.x, f1.y, f1.z, f1.w,
                             f2.x, f2.y, f2.z, f2.w};
#pragma unroll
        for (int ky = 0; ky < KS; ++ky) {
            const int o = ir - ky;                   // pending output row
            if (o >= 0 && o < 8) {
                float* a = acc[o % 7];
#pragma unroll
                for (int kx = 0; kx < KS; ++kx) {
                    const float wv = wreg[ky * KS + kx];
                    a[0] += wv * v[1 + kx];
                    a[1] += wv * v[2 + kx];
                    a[2] += wv * v[3 + kx];
                    a[3] += wv * v[4 + kx];
                }
            }
        }
        if (ir >= 6) {                               // output row ir-6 complete
            float* a = acc[(ir - 6) % 7];
            float4 o4 = make_float4(a[0] + bv, a[1] + bv, a[2] + bv, a[3] + bv);
            *((float4*)(outp + (size_t)(ir - 6) * WW)) = o4;
            a[0] = a[1] = a[2] = a[3] = 0.f;
        }
    }
}

extern "C" void kernel_launch(void* const* d_in, const int* in_sizes, int n_in,
                              void* d_out, int out_size, void* d_ws, size_t ws_size,
                              hipStream_t stream) {
    const float* x     = (const float*)d_in[0];
    const float* w1    = (const float*)d_in[1];
    const float* gamma = (const float*)d_in[2];
    const float* beta  = (const float*)d_in[3];
    const float* mean  = (const float*)d_in[4];
    const float* var   = (const float*)d_in[5];
    const float* w2    = (const float*)d_in[6];
    const float* b2    = (const float*)d_in[7];
    const float* bias  = (const float*)d_in[8];
    float* out = (float*)d_out;

    float* pooled = (float*)d_ws;                    // B*DIM floats

    pool_kernel<<<BATCH * DIM, 256, 0, stream>>>(x, pooled);
    dwconv_fused_kernel<<<BATCH * DIM * 2, 256, 0, stream>>>(
        x, pooled, w1, gamma, beta, mean, var, w2, b2, bias, out);
}